// Round 5
// baseline (5794.699 us; speedup 1.0000x reference)
//
#include <hip/hip_runtime.h>
#include <hip/hip_bf16.h>

#define IN_SIZE 256
#define HID 32
#define OUTC 64
#define EPSN 1e-12f

// ---------------- GEMM1: h = relu(features @ W1 + b1), plus inv_norm ----------------
// block = 256 threads = 8 nodes x 32 cols. W1 (32KB) + 8 feature rows (8KB) staged in LDS.
__global__ __launch_bounds__(256) void k_gemm1(const float* __restrict__ feat,
                                               const float* __restrict__ W1,
                                               const float* __restrict__ b1,
                                               float* __restrict__ h,
                                               float* __restrict__ inv_norm,
                                               int nNodes) {
    __shared__ float sW[IN_SIZE * HID];   // [k][col], 32KB
    __shared__ float sF[8 * IN_SIZE];     // 8 rows, 8KB
    const int t = threadIdx.x;
    const int nodeBase = blockIdx.x * 8;

    // stage W1 (coalesced float4)
    for (int i = t * 4; i < IN_SIZE * HID; i += 256 * 4) {
        *(float4*)(sW + i) = *(const float4*)(W1 + i);
    }
    // stage 8 feature rows (coalesced float4)
    for (int i = t * 4; i < 8 * IN_SIZE; i += 256 * 4) {
        int node = nodeBase + (i >> 8);
        float4 v = make_float4(0.f, 0.f, 0.f, 0.f);
        if (node < nNodes) v = *(const float4*)(feat + (size_t)nodeBase * IN_SIZE + i);
        *(float4*)(sF + i) = v;
    }
    __syncthreads();

    const int col = t & 31;
    const int local = t >> 5;
    const int node = nodeBase + local;

    float acc = b1[col];
    const float* fr = sF + local * IN_SIZE;
#pragma unroll 8
    for (int k = 0; k < IN_SIZE; ++k) {
        acc += fr[k] * sW[k * HID + col];
    }
    acc = fmaxf(acc, 0.f);  // relu

    // row sum-of-squares across the 32-lane group
    float ss = acc * acc;
    for (int off = 16; off; off >>= 1) ss += __shfl_xor(ss, off, 32);

    if (node < nNodes) {
        h[(size_t)node * HID + col] = acc;
        if (col == 0) inv_norm[node] = 1.0f / fmaxf(sqrtf(ss), EPSN);
    }
}

// ---------------- Edge pass 1: e = exp(beta * cos(h_dst, h_src)); s[dst] += e ----------------
__global__ __launch_bounds__(256) void k_edge_logits(const int* __restrict__ src,
                                                     const int* __restrict__ dst,
                                                     const float* __restrict__ h,
                                                     const float* __restrict__ inv_norm,
                                                     const float* __restrict__ betas, int layer,
                                                     float* __restrict__ e_buf,
                                                     float* __restrict__ s,
                                                     int nEdges) {
    int e = blockIdx.x * 256 + threadIdx.x;
    if (e >= nEdges) return;
    int a = src[e], b = dst[e];
    const float4* ha = (const float4*)(h + (size_t)a * HID);
    const float4* hb = (const float4*)(h + (size_t)b * HID);
    float dot = 0.f;
#pragma unroll
    for (int i = 0; i < 8; ++i) {
        float4 x = ha[i], y = hb[i];
        dot += x.x * y.x + x.y * y.y + x.z * y.z + x.w * y.w;
    }
    float beta = betas[layer];
    float logit = beta * (dot * inv_norm[a] * inv_norm[b]);   // in [-|beta|, |beta|]
    float ex = __expf(logit);                                  // max-free softmax (no overflow)
    e_buf[e] = ex;
    atomicAdd(&s[b], ex);
}

// ---------------- Edge pass 2: agg[dst] += (e/s[dst]) * h[src] ----------------
__global__ __launch_bounds__(256) void k_edge_aggregate(const int* __restrict__ src,
                                                        const int* __restrict__ dst,
                                                        const float* __restrict__ h,
                                                        const float* __restrict__ e_buf,
                                                        const float* __restrict__ s,
                                                        float* __restrict__ agg,
                                                        int nEdges) {
    int e = blockIdx.x * 256 + threadIdx.x;
    if (e >= nEdges) return;
    int a = src[e], b = dst[e];
    float alpha = e_buf[e] / s[b];
    const float4* ha = (const float4*)(h + (size_t)a * HID);
    float* out = agg + (size_t)b * HID;
#pragma unroll
    for (int i = 0; i < 8; ++i) {
        float4 x = ha[i];
        atomicAdd(out + i * 4 + 0, alpha * x.x);
        atomicAdd(out + i * 4 + 1, alpha * x.y);
        atomicAdd(out + i * 4 + 2, alpha * x.z);
        atomicAdd(out + i * 4 + 3, alpha * x.w);
    }
}

// ---------------- Node pass: h = relu(agg), inv_norm for next layer ----------------
__global__ __launch_bounds__(256) void k_relu_norm(const float* __restrict__ agg,
                                                   float* __restrict__ h,
                                                   float* __restrict__ inv_norm,
                                                   int nNodes) {
    int t = blockIdx.x * 256 + threadIdx.x;
    int node = t >> 5, col = t & 31;
    if (node >= nNodes) return;
    float v = fmaxf(agg[t], 0.f);
    float ss = v * v;
    for (int off = 16; off; off >>= 1) ss += __shfl_xor(ss, off, 32);
    h[t] = v;
    if (col == 0) inv_norm[node] = 1.0f / fmaxf(sqrtf(ss), EPSN);
}

// ---------------- GEMM2 + log_softmax: one wave per node ----------------
__global__ __launch_bounds__(256) void k_out(const float* __restrict__ h,
                                             const float* __restrict__ W2,
                                             const float* __restrict__ b2,
                                             float* __restrict__ out,
                                             int nNodes) {
    __shared__ float sW[HID * OUTC];  // 8KB, [k][j]
    const int t = threadIdx.x;
    for (int i = t * 4; i < HID * OUTC; i += 256 * 4) {
        *(float4*)(sW + i) = *(const float4*)(W2 + i);
    }
    __syncthreads();

    const int lane = t & 63;
    const int wv = t >> 6;
    const int node = blockIdx.x * 4 + wv;
    if (node >= nNodes) return;

    const float* hr = h + (size_t)node * HID;
    float acc = b2[lane];
#pragma unroll
    for (int k = 0; k < HID; ++k) {
        acc += hr[k] * sW[k * OUTC + lane];
    }
    // log_softmax over the 64 lanes
    float m = acc;
    for (int off = 32; off; off >>= 1) m = fmaxf(m, __shfl_xor(m, off));
    float ex = __expf(acc - m);
    float sum = ex;
    for (int off = 32; off; off >>= 1) sum += __shfl_xor(sum, off);
    out[(size_t)node * OUTC + lane] = acc - m - logf(sum);
}

extern "C" void kernel_launch(void* const* d_in, const int* in_sizes, int n_in,
                              void* d_out, int out_size, void* d_ws, size_t ws_size,
                              hipStream_t stream) {
    const int*   edge  = (const int*)d_in[0];    // [2, E] int32
    const float* feat  = (const float*)d_in[1];  // [N, 256]
    const float* W1    = (const float*)d_in[2];  // [256, 32]
    const float* b1    = (const float*)d_in[3];  // [32]
    const float* betas = (const float*)d_in[4];  // [2]
    const float* W2    = (const float*)d_in[5];  // [32, 64]
    const float* b2    = (const float*)d_in[6];  // [64]
    float* out = (float*)d_out;

    const int E = in_sizes[0] / 2;
    const int N = in_sizes[1] / IN_SIZE;
    const int* src = edge;
    const int* dst = edge + E;

    // workspace layout (floats)
    float* ws       = (float*)d_ws;
    float* h        = ws;                          // N*32
    float* agg      = h + (size_t)N * HID;         // N*32
    float* e_buf    = agg + (size_t)N * HID;       // E
    float* s        = e_buf + E;                   // N
    float* inv_norm = s + N;                       // N
    // total ~= 8.3M floats ~= 33MB

    k_gemm1<<<(N + 7) / 8, 256, 0, stream>>>(feat, W1, b1, h, inv_norm, N);

    for (int layer = 0; layer < 2; ++layer) {
        hipMemsetAsync(s, 0, (size_t)N * sizeof(float), stream);
        hipMemsetAsync(agg, 0, (size_t)N * HID * sizeof(float), stream);
        k_edge_logits<<<(E + 255) / 256, 256, 0, stream>>>(src, dst, h, inv_norm,
                                                           betas, layer, e_buf, s, E);
        k_edge_aggregate<<<(E + 255) / 256, 256, 0, stream>>>(src, dst, h, e_buf, s, agg, E);
        k_relu_norm<<<((size_t)N * HID + 255) / 256, 256, 0, stream>>>(agg, h, inv_norm, N);
    }

    k_out<<<(N + 3) / 4, 256, 0, stream>>>(h, W2, b2, out, N);
}

// Round 6
// 644.732 us; speedup vs baseline: 8.9878x; 8.9878x over previous
//
#include <hip/hip_runtime.h>
#include <hip/hip_bf16.h>

#define IN_SIZE 256
#define HID 32
#define OUTC 64
#define EPSN 1e-12f

// ---------------- GEMM1: h = relu(features @ W1 + b1), plus inv_norm ----------------
__global__ __launch_bounds__(256) void k_gemm1(const float* __restrict__ feat,
                                               const float* __restrict__ W1,
                                               const float* __restrict__ b1,
                                               float* __restrict__ h,
                                               float* __restrict__ inv_norm,
                                               int nNodes) {
    __shared__ float sW[IN_SIZE * HID];   // 32KB
    __shared__ float sF[8 * IN_SIZE];     // 8KB
    const int t = threadIdx.x;
    const int nodeBase = blockIdx.x * 8;

    for (int i = t * 4; i < IN_SIZE * HID; i += 256 * 4) {
        *(float4*)(sW + i) = *(const float4*)(W1 + i);
    }
    for (int i = t * 4; i < 8 * IN_SIZE; i += 256 * 4) {
        int node = nodeBase + (i >> 8);
        float4 v = make_float4(0.f, 0.f, 0.f, 0.f);
        if (node < nNodes) v = *(const float4*)(feat + (size_t)nodeBase * IN_SIZE + i);
        *(float4*)(sF + i) = v;
    }
    __syncthreads();

    const int col = t & 31;
    const int local = t >> 5;
    const int node = nodeBase + local;

    float acc = b1[col];
    const float* fr = sF + local * IN_SIZE;
#pragma unroll 8
    for (int k = 0; k < IN_SIZE; ++k) {
        acc += fr[k] * sW[k * HID + col];
    }
    acc = fmaxf(acc, 0.f);

    float ss = acc * acc;
    for (int off = 16; off; off >>= 1) ss += __shfl_xor(ss, off, 32);

    if (node < nNodes) {
        h[(size_t)node * HID + col] = acc;
        if (col == 0) inv_norm[node] = 1.0f / fmaxf(sqrtf(ss), EPSN);
    }
}

// ---------------- CSR build ----------------
__global__ __launch_bounds__(256) void k_count(const int* __restrict__ dst,
                                               int* __restrict__ cnt, int nEdges) {
    int e = blockIdx.x * 256 + threadIdx.x;
    if (e < nEdges) atomicAdd(&cnt[dst[e]], 1);
}

// exclusive block scan of cnt -> row_off, block totals -> bsum
__global__ __launch_bounds__(256) void k_scan1(const int* __restrict__ cnt,
                                               int* __restrict__ row_off,
                                               int* __restrict__ bsum, int n) {
    __shared__ int sd[256];
    int i = blockIdx.x * 256 + threadIdx.x;
    int v = (i < n) ? cnt[i] : 0;
    sd[threadIdx.x] = v;
    __syncthreads();
    for (int off = 1; off < 256; off <<= 1) {
        int tv = (threadIdx.x >= off) ? sd[threadIdx.x - off] : 0;
        __syncthreads();
        sd[threadIdx.x] += tv;
        __syncthreads();
    }
    if (i < n) row_off[i] = sd[threadIdx.x] - v;   // exclusive
    if (threadIdx.x == 255) bsum[blockIdx.x] = sd[255];
}

// single-block exclusive scan of bsum (nb <= 1024)
__global__ __launch_bounds__(1024) void k_scan2(int* __restrict__ bsum, int nb) {
    __shared__ int sd[1024];
    int t = threadIdx.x;
    int v = (t < nb) ? bsum[t] : 0;
    sd[t] = v;
    __syncthreads();
    for (int off = 1; off < 1024; off <<= 1) {
        int tv = (t >= off) ? sd[t - off] : 0;
        __syncthreads();
        sd[t] += tv;
        __syncthreads();
    }
    if (t < nb) bsum[t] = sd[t] - v;               // exclusive
}

__global__ __launch_bounds__(256) void k_scan3(int* __restrict__ row_off,
                                               const int* __restrict__ bsum,
                                               int n, int nEdges) {
    int i = blockIdx.x * 256 + threadIdx.x;
    if (i < n) row_off[i] += bsum[i >> 8];
    if (i == 0) row_off[n] = nEdges;
}

__global__ __launch_bounds__(256) void k_bucket(const int* __restrict__ src,
                                                const int* __restrict__ dst,
                                                const int* __restrict__ row_off,
                                                int* __restrict__ cursor,
                                                int* __restrict__ perm_src, int nEdges) {
    int e = blockIdx.x * 256 + threadIdx.x;
    if (e >= nEdges) return;
    int b = dst[e];
    int pos = atomicAdd(&cursor[b], 1);
    perm_src[row_off[b] + pos] = src[e];
}

// ---------------- Fused AGNN layer: softmax-weighted aggregation, relu, norm ----------------
// 32-lane group per dst node; lane owns one column. No atomics, one edge pass.
__global__ __launch_bounds__(256) void k_agnn(const int* __restrict__ row_off,
                                              const int* __restrict__ perm_src,
                                              const float* __restrict__ h_in,
                                              const float* __restrict__ inv_in,
                                              const float* __restrict__ betas, int layer,
                                              float* __restrict__ h_out,
                                              float* __restrict__ inv_out,
                                              int nNodes) {
    const int node = blockIdx.x * 8 + (threadIdx.x >> 5);
    const int col = threadIdx.x & 31;
    if (node >= nNodes) return;

    const float hd = h_in[(size_t)node * HID + col];
    const float invd = inv_in[node];
    const float beta = betas[layer];

    const int beg = row_off[node], end = row_off[node + 1];
    float sum_e = 0.f, acc = 0.f;

    for (int j = beg; j < end; ++j) {
        int a = perm_src[j];                         // uniform across the 32-group
        float hs = h_in[(size_t)a * HID + col];      // coalesced 128B row read
        float p = hd * hs;
#pragma unroll
        for (int off = 16; off; off >>= 1) p += __shfl_xor(p, off, 32);
        float e = __expf(beta * p * invd * inv_in[a]);  // logit in [-|beta|,|beta|]
        sum_e += e;
        acc += e * hs;
    }

    float v = (end > beg) ? fmaxf(acc / sum_e, 0.f) : 0.f;  // relu(agg); empty segment -> 0
    float ss = v * v;
#pragma unroll
    for (int off = 16; off; off >>= 1) ss += __shfl_xor(ss, off, 32);

    h_out[(size_t)node * HID + col] = v;
    if (col == 0) inv_out[node] = 1.0f / fmaxf(sqrtf(ss), EPSN);
}

// ---------------- GEMM2 + log_softmax: one wave per node ----------------
__global__ __launch_bounds__(256) void k_out(const float* __restrict__ h,
                                             const float* __restrict__ W2,
                                             const float* __restrict__ b2,
                                             float* __restrict__ out,
                                             int nNodes) {
    __shared__ float sW[HID * OUTC];  // 8KB
    const int t = threadIdx.x;
    for (int i = t * 4; i < HID * OUTC; i += 256 * 4) {
        *(float4*)(sW + i) = *(const float4*)(W2 + i);
    }
    __syncthreads();

    const int lane = t & 63;
    const int wv = t >> 6;
    const int node = blockIdx.x * 4 + wv;
    if (node >= nNodes) return;

    const float* hr = h + (size_t)node * HID;
    float acc = b2[lane];
#pragma unroll
    for (int k = 0; k < HID; ++k) {
        acc += hr[k] * sW[k * OUTC + lane];
    }
    float m = acc;
    for (int off = 32; off; off >>= 1) m = fmaxf(m, __shfl_xor(m, off));
    float ex = __expf(acc - m);
    float sum = ex;
    for (int off = 32; off; off >>= 1) sum += __shfl_xor(sum, off);
    out[(size_t)node * OUTC + lane] = acc - m - logf(sum);
}

extern "C" void kernel_launch(void* const* d_in, const int* in_sizes, int n_in,
                              void* d_out, int out_size, void* d_ws, size_t ws_size,
                              hipStream_t stream) {
    const int*   edge  = (const int*)d_in[0];    // [2, E] int32
    const float* feat  = (const float*)d_in[1];  // [N, 256]
    const float* W1    = (const float*)d_in[2];  // [256, 32]
    const float* b1    = (const float*)d_in[3];  // [32]
    const float* betas = (const float*)d_in[4];  // [2]
    const float* W2    = (const float*)d_in[5];  // [32, 64]
    const float* b2    = (const float*)d_in[6];  // [64]
    float* out = (float*)d_out;

    const int E = in_sizes[0] / 2;
    const int N = in_sizes[1] / IN_SIZE;
    const int* src = edge;
    const int* dst = edge + E;

    // workspace layout
    float* h0   = (float*)d_ws;                    // N*32
    float* h1   = h0 + (size_t)N * HID;            // N*32
    float* inv0 = h1 + (size_t)N * HID;            // N
    float* inv1 = inv0 + N;                        // N
    int* row_off  = (int*)(inv1 + N);              // N+1
    int* cnt      = row_off + (N + 1);             // N (deg, then cursor)
    int* perm_src = cnt + N;                       // E
    int* bsum     = perm_src + E;                  // <=1024
    // total ~= 33.7 MB

    const int nb = (N + 255) / 256;                // 391 blocks (<=1024 required by k_scan2)

    // ---- CSR build (graph static across layers) ----
    hipMemsetAsync(cnt, 0, (size_t)N * sizeof(int), stream);
    k_count<<<(E + 255) / 256, 256, 0, stream>>>(dst, cnt, E);
    k_scan1<<<nb, 256, 0, stream>>>(cnt, row_off, bsum, N);
    k_scan2<<<1, 1024, 0, stream>>>(bsum, nb);
    k_scan3<<<nb, 256, 0, stream>>>(row_off, bsum, N, E);
    hipMemsetAsync(cnt, 0, (size_t)N * sizeof(int), stream);   // reuse as cursor
    k_bucket<<<(E + 255) / 256, 256, 0, stream>>>(src, dst, row_off, cnt, perm_src, E);

    // ---- input projection ----
    k_gemm1<<<(N + 7) / 8, 256, 0, stream>>>(feat, W1, b1, h0, inv0, N);

    // ---- two fused AGNN layers (ping-pong h0/h1) ----
    k_agnn<<<(N + 7) / 8, 256, 0, stream>>>(row_off, perm_src, h0, inv0, betas, 0, h1, inv1, N);
    k_agnn<<<(N + 7) / 8, 256, 0, stream>>>(row_off, perm_src, h1, inv1, betas, 1, h0, inv0, N);

    // ---- output projection + log_softmax ----
    k_out<<<(N + 3) / 4, 256, 0, stream>>>(h0, W2, b2, out, N);
}

// Round 7
// 608.971 us; speedup vs baseline: 9.5156x; 1.0587x over previous
//
#include <hip/hip_runtime.h>
#include <hip/hip_bf16.h>

#define IN_SIZE 256
#define HID 32
#define OUTC 64
#define EPSN 1e-12f

// ---------------- GEMM1: h = relu(features @ W1 + b1), plus inv_norm ----------------
__global__ __launch_bounds__(256) void k_gemm1(const float* __restrict__ feat,
                                               const float* __restrict__ W1,
                                               const float* __restrict__ b1,
                                               float* __restrict__ h,
                                               float* __restrict__ inv_norm,
                                               int nNodes) {
    __shared__ float sW[IN_SIZE * HID];   // 32KB
    __shared__ float sF[8 * IN_SIZE];     // 8KB
    const int t = threadIdx.x;
    const int nodeBase = blockIdx.x * 8;

    for (int i = t * 4; i < IN_SIZE * HID; i += 256 * 4) {
        *(float4*)(sW + i) = *(const float4*)(W1 + i);
    }
    for (int i = t * 4; i < 8 * IN_SIZE; i += 256 * 4) {
        int node = nodeBase + (i >> 8);
        float4 v = make_float4(0.f, 0.f, 0.f, 0.f);
        if (node < nNodes) v = *(const float4*)(feat + (size_t)nodeBase * IN_SIZE + i);
        *(float4*)(sF + i) = v;
    }
    __syncthreads();

    const int col = t & 31;
    const int local = t >> 5;
    const int node = nodeBase + local;

    float acc = b1[col];
    const float* fr = sF + local * IN_SIZE;
#pragma unroll 8
    for (int k = 0; k < IN_SIZE; ++k) {
        acc += fr[k] * sW[k * HID + col];
    }
    acc = fmaxf(acc, 0.f);

    float ss = acc * acc;
    for (int off = 16; off; off >>= 1) ss += __shfl_xor(ss, off, 32);

    if (node < nNodes) {
        h[(size_t)node * HID + col] = acc;
        if (col == 0) inv_norm[node] = 1.0f / fmaxf(sqrtf(ss), EPSN);
    }
}

// ---------------- CSR build ----------------
__global__ __launch_bounds__(256) void k_count(const int* __restrict__ dst,
                                               int* __restrict__ cnt, int nEdges) {
    int e = blockIdx.x * 256 + threadIdx.x;
    if (e < nEdges) atomicAdd(&cnt[dst[e]], 1);
}

// exclusive block scan of cnt -> row_off, block totals -> bsum
__global__ __launch_bounds__(256) void k_scan1(const int* __restrict__ cnt,
                                               int* __restrict__ row_off,
                                               int* __restrict__ bsum, int n) {
    __shared__ int sd[256];
    int i = blockIdx.x * 256 + threadIdx.x;
    int v = (i < n) ? cnt[i] : 0;
    sd[threadIdx.x] = v;
    __syncthreads();
    for (int off = 1; off < 256; off <<= 1) {
        int tv = (threadIdx.x >= off) ? sd[threadIdx.x - off] : 0;
        __syncthreads();
        sd[threadIdx.x] += tv;
        __syncthreads();
    }
    if (i < n) row_off[i] = sd[threadIdx.x] - v;   // exclusive
    if (threadIdx.x == 255) bsum[blockIdx.x] = sd[255];
}

// single-block exclusive scan of bsum (nb <= 1024)
__global__ __launch_bounds__(1024) void k_scan2(int* __restrict__ bsum, int nb) {
    __shared__ int sd[1024];
    int t = threadIdx.x;
    int v = (t < nb) ? bsum[t] : 0;
    sd[t] = v;
    __syncthreads();
    for (int off = 1; off < 1024; off <<= 1) {
        int tv = (t >= off) ? sd[t - off] : 0;
        __syncthreads();
        sd[t] += tv;
        __syncthreads();
    }
    if (t < nb) bsum[t] = sd[t] - v;               // exclusive
}

// adds block prefix; also initializes cursor[i] = row_off[i] (absolute-position bucketing)
__global__ __launch_bounds__(256) void k_scan3(int* __restrict__ row_off,
                                               const int* __restrict__ bsum,
                                               int* __restrict__ cursor,
                                               int n, int nEdges) {
    int i = blockIdx.x * 256 + threadIdx.x;
    if (i < n) {
        int r = row_off[i] + bsum[i >> 8];
        row_off[i] = r;
        cursor[i] = r;
    }
    if (i == 0) row_off[n] = nEdges;
}

__global__ __launch_bounds__(256) void k_bucket(const int* __restrict__ src,
                                                const int* __restrict__ dst,
                                                int* __restrict__ cursor,
                                                int* __restrict__ perm_src, int nEdges) {
    int e = blockIdx.x * 256 + threadIdx.x;
    if (e >= nEdges) return;
    int pos = atomicAdd(&cursor[dst[e]], 1);   // absolute position, no row_off gather
    perm_src[pos] = src[e];
}

// ---------------- Fused AGNN layer: one wave64 per node, 4 edges per iteration ----------------
// lane = (half = edge slot, col). Two independent accumulator pairs for ILP; no atomics.
__global__ __launch_bounds__(256) void k_agnn(const int* __restrict__ row_off,
                                              const int* __restrict__ perm_src,
                                              const float* __restrict__ h_in,
                                              const float* __restrict__ inv_in,
                                              const float* __restrict__ betas, int layer,
                                              float* __restrict__ h_out,
                                              float* __restrict__ inv_out,
                                              int nNodes) {
    const int node = blockIdx.x * 4 + (threadIdx.x >> 6);
    const int lane = threadIdx.x & 63;
    const int col  = lane & 31;
    const int half = lane >> 5;                  // 0 or 1: which edge of the pair
    if (node >= nNodes) return;

    const float hd   = h_in[(size_t)node * HID + col];
    const float invd = inv_in[node];
    const float beta = betas[layer];

    const int beg = row_off[node], end = row_off[node + 1];
    const int endm1 = end - 1;

    float sA = 0.f, sB = 0.f, accA = 0.f, accB = 0.f;

    for (int j = beg; j < end; j += 4) {
        int i0 = j + half;                       // edges j, j+1
        int i1 = j + 2 + half;                   // edges j+2, j+3
        int a0 = perm_src[min(i0, endm1)];
        int a1 = perm_src[min(i1, endm1)];
        float hs0 = h_in[(size_t)a0 * HID + col];   // 128B row gather per half
        float hs1 = h_in[(size_t)a1 * HID + col];
        float iv0 = inv_in[a0];                  // broadcast within half
        float iv1 = inv_in[a1];
        float p0 = hd * hs0;
        float p1 = hd * hs1;
#pragma unroll
        for (int off = 16; off; off >>= 1) {     // two interleaved 32-wide dot reduces
            p0 += __shfl_xor(p0, off, 32);
            p1 += __shfl_xor(p1, off, 32);
        }
        float e0 = (i0 < end) ? __expf(beta * p0 * invd * iv0) : 0.f;
        float e1 = (i1 < end) ? __expf(beta * p1 * invd * iv1) : 0.f;
        sA += e0; accA += e0 * hs0;
        sB += e1; accB += e1 * hs1;
    }

    float sum_e = sA + sB;
    float acc = accA + accB;
    sum_e += __shfl_xor(sum_e, 32);              // combine halves (width 64)
    acc   += __shfl_xor(acc, 32);

    float v = (end > beg) ? fmaxf(acc / sum_e, 0.f) : 0.f;  // relu(agg); empty segment -> 0
    float ss = v * v;
#pragma unroll
    for (int off = 16; off; off >>= 1) ss += __shfl_xor(ss, off, 32);

    if (half == 0) {
        h_out[(size_t)node * HID + col] = v;
        if (col == 0) inv_out[node] = 1.0f / fmaxf(sqrtf(ss), EPSN);
    }
}

// ---------------- GEMM2 + log_softmax: one wave per node ----------------
__global__ __launch_bounds__(256) void k_out(const float* __restrict__ h,
                                             const float* __restrict__ W2,
                                             const float* __restrict__ b2,
                                             float* __restrict__ out,
                                             int nNodes) {
    __shared__ float sW[HID * OUTC];  // 8KB
    const int t = threadIdx.x;
    for (int i = t * 4; i < HID * OUTC; i += 256 * 4) {
        *(float4*)(sW + i) = *(const float4*)(W2 + i);
    }
    __syncthreads();

    const int lane = t & 63;
    const int wv = t >> 6;
    const int node = blockIdx.x * 4 + wv;
    if (node >= nNodes) return;

    const float* hr = h + (size_t)node * HID;
    float acc = b2[lane];
#pragma unroll
    for (int k = 0; k < HID; ++k) {
        acc += hr[k] * sW[k * OUTC + lane];
    }
    float m = acc;
    for (int off = 32; off; off >>= 1) m = fmaxf(m, __shfl_xor(m, off));
    float ex = __expf(acc - m);
    float sum = ex;
    for (int off = 32; off; off >>= 1) sum += __shfl_xor(sum, off);
    out[(size_t)node * OUTC + lane] = acc - m - logf(sum);
}

extern "C" void kernel_launch(void* const* d_in, const int* in_sizes, int n_in,
                              void* d_out, int out_size, void* d_ws, size_t ws_size,
                              hipStream_t stream) {
    const int*   edge  = (const int*)d_in[0];    // [2, E] int32
    const float* feat  = (const float*)d_in[1];  // [N, 256]
    const float* W1    = (const float*)d_in[2];  // [256, 32]
    const float* b1    = (const float*)d_in[3];  // [32]
    const float* betas = (const float*)d_in[4];  // [2]
    const float* W2    = (const float*)d_in[5];  // [32, 64]
    const float* b2    = (const float*)d_in[6];  // [64]
    float* out = (float*)d_out;

    const int E = in_sizes[0] / 2;
    const int N = in_sizes[1] / IN_SIZE;
    const int* src = edge;
    const int* dst = edge + E;

    // workspace layout
    float* h0   = (float*)d_ws;                    // N*32
    float* h1   = h0 + (size_t)N * HID;            // N*32
    float* inv0 = h1 + (size_t)N * HID;            // N
    float* inv1 = inv0 + N;                        // N
    int* row_off  = (int*)(inv1 + N);              // N+1
    int* cnt      = row_off + (N + 1);             // N (deg count, then cursor)
    int* perm_src = cnt + N;                       // E
    int* bsum     = perm_src + E;                  // <=1024
    // total ~= 33.7 MB

    const int nb = (N + 255) / 256;                // 391 blocks (<=1024 required by k_scan2)

    // ---- CSR build (graph static across layers) ----
    hipMemsetAsync(cnt, 0, (size_t)N * sizeof(int), stream);
    k_count<<<(E + 255) / 256, 256, 0, stream>>>(dst, cnt, E);
    k_scan1<<<nb, 256, 0, stream>>>(cnt, row_off, bsum, N);
    k_scan2<<<1, 1024, 0, stream>>>(bsum, nb);
    k_scan3<<<nb, 256, 0, stream>>>(row_off, bsum, cnt, N, E);   // cnt becomes cursor
    k_bucket<<<(E + 255) / 256, 256, 0, stream>>>(src, dst, cnt, perm_src, E);

    // ---- input projection ----
    k_gemm1<<<(N + 7) / 8, 256, 0, stream>>>(feat, W1, b1, h0, inv0, N);

    // ---- two fused AGNN layers (ping-pong h0/h1) ----
    k_agnn<<<(N + 3) / 4, 256, 0, stream>>>(row_off, perm_src, h0, inv0, betas, 0, h1, inv1, N);
    k_agnn<<<(N + 3) / 4, 256, 0, stream>>>(row_off, perm_src, h1, inv1, betas, 1, h0, inv0, N);

    // ---- output projection + log_softmax ----
    k_out<<<(N + 3) / 4, 256, 0, stream>>>(h0, W2, b2, out, N);
}

// Round 8
// 486.916 us; speedup vs baseline: 11.9008x; 1.2507x over previous
//
#include <hip/hip_runtime.h>
#include <hip/hip_bf16.h>

#define IN_SIZE 256
#define HID 32
#define OUTC 64
#define EPSN 1e-12f
#define BSHIFT 10          // coarse bucket = dst >> 10 (1024 nodes per bucket)
#define MAXBUCK 128        // >= nbuck (98 for N=100000)
#define BCAP 20480         // bucket capacity for LDS stage (mean 16384 + 32 sigma)

// ---------------- GEMM1: h = relu(features @ W1 + b1) -> bf16, plus inv_norm ----------------
__global__ __launch_bounds__(256) void k_gemm1(const float* __restrict__ feat,
                                               const float* __restrict__ W1,
                                               const float* __restrict__ b1,
                                               __hip_bfloat16* __restrict__ h_bf,
                                               float* __restrict__ inv_norm,
                                               int nNodes) {
    __shared__ float sW[IN_SIZE * HID];   // 32KB
    __shared__ float sF[8 * IN_SIZE];     // 8KB
    const int t = threadIdx.x;
    const int nodeBase = blockIdx.x * 8;

    for (int i = t * 4; i < IN_SIZE * HID; i += 256 * 4) {
        *(float4*)(sW + i) = *(const float4*)(W1 + i);
    }
    for (int i = t * 4; i < 8 * IN_SIZE; i += 256 * 4) {
        int node = nodeBase + (i >> 8);
        float4 v = make_float4(0.f, 0.f, 0.f, 0.f);
        if (node < nNodes) v = *(const float4*)(feat + (size_t)nodeBase * IN_SIZE + i);
        *(float4*)(sF + i) = v;
    }
    __syncthreads();

    const int col = t & 31;
    const int local = t >> 5;
    const int node = nodeBase + local;

    float acc = b1[col];
    const float* fr = sF + local * IN_SIZE;
#pragma unroll 8
    for (int k = 0; k < IN_SIZE; ++k) {
        acc += fr[k] * sW[k * HID + col];
    }
    acc = fmaxf(acc, 0.f);

    __hip_bfloat16 q = __float2bfloat16(acc);
    float accq = __bfloat162float(q);          // norm over the values actually stored
    float ss = accq * accq;
    for (int off = 16; off; off >>= 1) ss += __shfl_xor(ss, off, 32);

    if (node < nNodes) {
        h_bf[(size_t)node * HID + col] = q;
        if (col == 0) inv_norm[node] = 1.0f / fmaxf(sqrtf(ss), EPSN);
    }
}

// ---------------- CSR build: two-level LDS-staged counting sort ----------------
// coarse histogram (98 buckets), per-block LDS then global
__global__ __launch_bounds__(256) void k_hist(const int* __restrict__ dst,
                                              int* __restrict__ g_bhist, int nEdges) {
    __shared__ int lh[MAXBUCK];
    const int t = threadIdx.x;
    if (t < MAXBUCK) lh[t] = 0;
    __syncthreads();
    const int base = blockIdx.x * 4096;
    for (int i = 0; i < 16; ++i) {
        int e = base + i * 256 + t;
        if (e < nEdges) atomicAdd(&lh[dst[e] >> BSHIFT], 1);
    }
    __syncthreads();
    if (t < MAXBUCK && lh[t]) atomicAdd(&g_bhist[t], lh[t]);
}

// tiny serial scan (98 values) + cursor init
__global__ void k_bscan(const int* __restrict__ g_bhist, int* __restrict__ g_bbase,
                        int* __restrict__ g_bcursor, int nbuck) {
    if (threadIdx.x == 0) {
        int acc = 0;
        for (int b = 0; b < nbuck; ++b) { g_bbase[b] = acc; g_bcursor[b] = acc; acc += g_bhist[b]; }
        g_bbase[nbuck] = acc;
    }
}

// partition edges into coarse buckets; per-(block,bucket) writes are consecutive runs
__global__ __launch_bounds__(256) void k_partition(const int* __restrict__ src,
                                                   const int* __restrict__ dst,
                                                   int* __restrict__ g_bcursor,
                                                   unsigned* __restrict__ ebuf, int nEdges) {
    __shared__ int lh[MAXBUCK], lbase[MAXBUCK];
    const int t = threadIdx.x;
    if (t < MAXBUCK) lh[t] = 0;
    __syncthreads();
    const int base = blockIdx.x * 4096;
    int mydst[16], mysrc[16];
    for (int i = 0; i < 16; ++i) {
        int e = base + i * 256 + t;
        int d = (e < nEdges) ? dst[e] : -1;
        mydst[i] = d;
        mysrc[i] = (e < nEdges) ? src[e] : 0;
        if (d >= 0) atomicAdd(&lh[d >> BSHIFT], 1);
    }
    __syncthreads();
    if (t < MAXBUCK) {
        int c = lh[t];
        lbase[t] = c ? atomicAdd(&g_bcursor[t], c) : 0;
        lh[t] = 0;                               // reuse as local cursor
    }
    __syncthreads();
    for (int i = 0; i < 16; ++i) {
        int d = mydst[i];
        if (d >= 0) {
            int b = d >> BSHIFT;
            int pos = atomicAdd(&lh[b], 1);
            ebuf[lbase[b] + pos] = ((unsigned)(d & 1023) << 20) | (unsigned)mysrc[i];
        }
    }
}

// in-place per-bucket sort by dst: LDS stage -> per-dst hist/scan -> LDS-local scatter
// also emits row_off for this bucket's node range (and row_off[N]=E)
__global__ __launch_bounds__(1024) void k_bsort(const int* __restrict__ g_bbase,
                                                unsigned* __restrict__ ebuf,
                                                int* __restrict__ row_off, int N) {
    __shared__ unsigned se[BCAP];   // 80KB
    __shared__ int lh[1024], ls[1024];
    const int b = blockIdx.x;
    const int t = threadIdx.x;
    const int base = g_bbase[b], end = g_bbase[b + 1];
    const int len = end - base;

    for (int i = t; i < len; i += 1024) se[i] = ebuf[base + i];
    lh[t] = 0;
    __syncthreads();
    for (int i = t; i < len; i += 1024) atomicAdd(&lh[se[i] >> 20], 1);
    __syncthreads();

    // Hillis-Steele inclusive scan of lh -> ls
    int v = lh[t];
    ls[t] = v;
    __syncthreads();
    for (int off = 1; off < 1024; off <<= 1) {
        int tv = (t >= off) ? ls[t - off] : 0;
        __syncthreads();
        ls[t] += tv;
        __syncthreads();
    }
    int excl = ls[t] - v;

    int node = (b << BSHIFT) + t;
    if (node <= N) row_off[node] = base + excl;  // node==N lands exactly on E
    lh[t] = excl;                                 // reuse as per-dst cursor
    __syncthreads();

    for (int i = t; i < len; i += 1024) {
        unsigned p = se[i];
        int pos = atomicAdd(&lh[p >> 20], 1);
        ebuf[base + pos] = p & 0xFFFFFu;          // final perm_src (in place)
    }
}

// ---------------- Fused AGNN layer: one wave64 per node, 4 edges/iter, bf16 gathers ----------------
__global__ __launch_bounds__(256) void k_agnn(const int* __restrict__ row_off,
                                              const int* __restrict__ perm_src,
                                              const __hip_bfloat16* __restrict__ h_in,
                                              const float* __restrict__ inv_in,
                                              const float* __restrict__ betas, int layer,
                                              __hip_bfloat16* __restrict__ h_out_bf,
                                              float* __restrict__ h_out_f32,
                                              float* __restrict__ inv_out,
                                              int nNodes) {
    const int node = blockIdx.x * 4 + (threadIdx.x >> 6);
    const int lane = threadIdx.x & 63;
    const int col  = lane & 31;
    const int half = lane >> 5;
    if (node >= nNodes) return;

    const float hd   = __bfloat162float(h_in[(size_t)node * HID + col]);
    const float invd = inv_in[node];
    const float beta = betas[layer];

    const int beg = row_off[node], end = row_off[node + 1];
    const int endm1 = end - 1;

    float sA = 0.f, sB = 0.f, accA = 0.f, accB = 0.f;

    for (int j = beg; j < end; j += 4) {
        int i0 = j + half;
        int i1 = j + 2 + half;
        int a0 = perm_src[min(i0, endm1)];
        int a1 = perm_src[min(i1, endm1)];
        float hs0 = __bfloat162float(h_in[(size_t)a0 * HID + col]);  // 64B row = 1 line
        float hs1 = __bfloat162float(h_in[(size_t)a1 * HID + col]);
        float iv0 = inv_in[a0];
        float iv1 = inv_in[a1];
        float p0 = hd * hs0;
        float p1 = hd * hs1;
#pragma unroll
        for (int off = 16; off; off >>= 1) {
            p0 += __shfl_xor(p0, off, 32);
            p1 += __shfl_xor(p1, off, 32);
        }
        float e0 = (i0 < end) ? __expf(beta * p0 * invd * iv0) : 0.f;
        float e1 = (i1 < end) ? __expf(beta * p1 * invd * iv1) : 0.f;
        sA += e0; accA += e0 * hs0;
        sB += e1; accB += e1 * hs1;
    }

    float sum_e = sA + sB;
    float acc = accA + accB;
    sum_e += __shfl_xor(sum_e, 32);
    acc   += __shfl_xor(acc, 32);

    float vraw = (end > beg) ? fmaxf(acc / sum_e, 0.f) : 0.f;
    __hip_bfloat16 q = __float2bfloat16(vraw);
    float vq = __bfloat162float(q);               // norm over stored values
    float ss = vq * vq;
#pragma unroll
    for (int off = 16; off; off >>= 1) ss += __shfl_xor(ss, off, 32);

    if (half == 0) {
        h_out_bf[(size_t)node * HID + col] = q;
        if (h_out_f32) h_out_f32[(size_t)node * HID + col] = vraw;
        if (col == 0) inv_out[node] = 1.0f / fmaxf(sqrtf(ss), EPSN);
    }
}

// ---------------- GEMM2 + log_softmax: one wave per node ----------------
__global__ __launch_bounds__(256) void k_out(const float* __restrict__ h,
                                             const float* __restrict__ W2,
                                             const float* __restrict__ b2,
                                             float* __restrict__ out,
                                             int nNodes) {
    __shared__ float sW[HID * OUTC];  // 8KB
    const int t = threadIdx.x;
    for (int i = t * 4; i < HID * OUTC; i += 256 * 4) {
        *(float4*)(sW + i) = *(const float4*)(W2 + i);
    }
    __syncthreads();

    const int lane = t & 63;
    const int wv = t >> 6;
    const int node = blockIdx.x * 4 + wv;
    if (node >= nNodes) return;

    const float* hr = h + (size_t)node * HID;
    float acc = b2[lane];
#pragma unroll
    for (int k = 0; k < HID; ++k) {
        acc += hr[k] * sW[k * OUTC + lane];
    }
    float m = acc;
    for (int off = 32; off; off >>= 1) m = fmaxf(m, __shfl_xor(m, off));
    float ex = __expf(acc - m);
    float sum = ex;
    for (int off = 32; off; off >>= 1) sum += __shfl_xor(sum, off);
    out[(size_t)node * OUTC + lane] = acc - m - logf(sum);
}

extern "C" void kernel_launch(void* const* d_in, const int* in_sizes, int n_in,
                              void* d_out, int out_size, void* d_ws, size_t ws_size,
                              hipStream_t stream) {
    const int*   edge  = (const int*)d_in[0];    // [2, E] int32
    const float* feat  = (const float*)d_in[1];  // [N, 256]
    const float* W1    = (const float*)d_in[2];  // [256, 32]
    const float* b1    = (const float*)d_in[3];  // [32]
    const float* betas = (const float*)d_in[4];  // [2]
    const float* W2    = (const float*)d_in[5];  // [32, 64]
    const float* b2    = (const float*)d_in[6];  // [64]
    float* out = (float*)d_out;

    const int E = in_sizes[0] / 2;
    const int N = in_sizes[1] / IN_SIZE;
    const int* src = edge;
    const int* dst = edge + E;
    const int nbuck = (N + 1023) >> BSHIFT;      // 98

    // workspace layout (~33.2 MB)
    __hip_bfloat16* h0b = (__hip_bfloat16*)d_ws;           // N*32 bf16, 6.4MB
    __hip_bfloat16* h1b = h0b + (size_t)N * HID;           // 6.4MB
    float* h2   = (float*)(h1b + (size_t)N * HID);         // N*32 f32, 12.8MB
    float* inv0 = h2 + (size_t)N * HID;                    // N
    float* inv1 = inv0 + N;                                // N
    int* row_off = (int*)(inv1 + N);                       // N+1
    unsigned* ebuf = (unsigned*)(row_off + N + 1);         // E (binned pairs, then perm_src in place)
    int* g_bhist   = (int*)(ebuf + E);                     // MAXBUCK
    int* g_bbase   = g_bhist + MAXBUCK;                    // MAXBUCK+1
    int* g_bcursor = g_bbase + MAXBUCK + 1;                // MAXBUCK

    const int nEblk = (E + 4095) / 4096;                   // 391

    // ---- CSR build: hist -> scan -> partition -> per-bucket LDS sort ----
    hipMemsetAsync(g_bhist, 0, MAXBUCK * sizeof(int), stream);
    k_hist<<<nEblk, 256, 0, stream>>>(dst, g_bhist, E);
    k_bscan<<<1, 64, 0, stream>>>(g_bhist, g_bbase, g_bcursor, nbuck);
    k_partition<<<nEblk, 256, 0, stream>>>(src, dst, g_bcursor, ebuf, E);
    k_bsort<<<nbuck, 1024, 0, stream>>>(g_bbase, ebuf, row_off, N);

    // ---- input projection (bf16 h0) ----
    k_gemm1<<<(N + 7) / 8, 256, 0, stream>>>(feat, W1, b1, h0b, inv0, N);

    // ---- two fused AGNN layers ----
    k_agnn<<<(N + 3) / 4, 256, 0, stream>>>(row_off, (const int*)ebuf, h0b, inv0, betas, 0,
                                            h1b, nullptr, inv1, N);
    k_agnn<<<(N + 3) / 4, 256, 0, stream>>>(row_off, (const int*)ebuf, h1b, inv1, betas, 1,
                                            h0b, h2, inv0, N);

    // ---- output projection + log_softmax ----
    k_out<<<(N + 3) / 4, 256, 0, stream>>>(h2, W2, b2, out, N);
}